// Round 3
// baseline (252.900 us; speedup 1.0000x reference)
//
#include <hip/hip_runtime.h>
#include <hip/hip_bf16.h>
#include <cstdint>
#include <cstddef>

// TT-dense: y = relu(x @ M + b)
// x: [4096,4096] f32, M: TT(cores r=1,16,16,16,1, dims 8^4 x 8^4), out f32.
//
// Route: materialize M^T in bf16, convert x to bf16, one 4096^3 bf16 MFMA
// GEMM with fused bias+relu.
// History: R5 full-rate swizzle -> 0 conflicts, 160us GEMM (m97 ceiling);
//   R8 256^2 8-wave dbuf 4-phase -> 135us (MfmaUtil 43.6%); R9 barrier
//   minimization -> 132.6us (46.4%) NEUTRAL. Cycle model: per K-tile
//   MFMA 2066 cyc + LDS 2800 cyc ~= observed 4973 -> pipes fully SERIAL.
//   Cause: each phase's ds_reads feed the SAME phase's MFMA, so waits sit
//   right before the MFMA cluster; all waves stall together.
// R10: one-phase-ahead register prefetch. Phase q issues ds_reads for quad
//   q+1 into the alternate frag set (afE/afO), then runs quad q's MFMA with
//   no intervening wait -> next reads drain UNDER current MFMA. B read once
//   per tile (8 reads at preceding q3, alternating b0v/b1v). One barrier
//   per phase. Stages: A(t+1)->other buf @q0,q1; B(t+2)->cur buf @q1,q2;
//   vmcnt(4) once per tile at q2-end (tail vmcnt(0)). New pole = LDS unit
//   ~2900 cyc/tile -> predict ~95us GEMM.

#define GM 4096
#define GN 4096
#define GK 4096
#define NT (GK / 64)

typedef __attribute__((ext_vector_type(8))) short short8_t;
typedef __attribute__((ext_vector_type(4))) float float4_t;

__device__ __forceinline__ unsigned short f2bf(float f) {
  union { float f; uint32_t u; } v; v.f = f;
  uint32_t u = v.u;
  uint32_t r = (u + 0x7fffu + ((u >> 16) & 1u)) >> 16;  // RNE
  return (unsigned short)r;
}

// ---------------------------------------------------------------------------
// Kernel 1 (512 blocks, ~4us): merge core pairs.
// ---------------------------------------------------------------------------
__global__ __launch_bounds__(256) void prep_kernel(
    const float* __restrict__ c0, const float* __restrict__ c1,
    const float* __restrict__ c2, const float* __restrict__ c3,
    float* __restrict__ G01, float* __restrict__ G23t) {
  int idx = blockIdx.x * 256 + threadIdx.x;  // 0..131071
  if (idx < 65536) {
    int r2 = idx & 15;
    int b01 = (idx >> 4) & 63;
    int a01 = idx >> 10;
    int a0 = a01 >> 3, a1 = a01 & 7, b0 = b01 >> 3, b1 = b01 & 7;
    float s = 0.f;
#pragma unroll
    for (int r1 = 0; r1 < 16; ++r1)
      s += c0[(a0 * 8 + b0) * 16 + r1] * c1[((r1 * 8 + a1) * 8 + b1) * 16 + r2];
    G01[idx] = s;
  } else {
    int t = idx - 65536;  // t = r2*4096 + b23*64 + a23
    int a23 = t & 63;
    int b23 = (t >> 6) & 63;
    int r2 = t >> 12;
    int a2 = a23 >> 3, a3 = a23 & 7, b2 = b23 >> 3, b3 = b23 & 7;
    float s = 0.f;
#pragma unroll
    for (int r3 = 0; r3 < 16; ++r3)
      s += c2[((r2 * 8 + a2) * 8 + b2) * 16 + r3] * c3[(r3 * 8 + a3) * 8 + b3];
    G23t[t] = s;
  }
}

// ---------------------------------------------------------------------------
// Kernel 2 (fused, mutually independent halves).
// ---------------------------------------------------------------------------
__global__ __launch_bounds__(256) void mt_convert(
    const float* __restrict__ G01, const float* __restrict__ G23t,
    unsigned short* __restrict__ Mt,
    const float* __restrict__ x, unsigned short* __restrict__ xb) {
  int bid = blockIdx.x;
  int tid = threadIdx.x;
  if (bid < 1024) {
    int a01 = bid >> 4;
    int g = bid & 15;  // b01 = g*4 + j

    float acc[4][16];
#pragma unroll
    for (int j = 0; j < 4; ++j)
#pragma unroll
      for (int i = 0; i < 16; ++i) acc[j][i] = 0.f;

    for (int r2 = 0; r2 < 16; ++r2) {
      float gv[4];
#pragma unroll
      for (int j = 0; j < 4; ++j)
        gv[j] = G01[(a01 * 64 + g * 4 + j) * 16 + r2];  // block-uniform
      const float* src = G23t + r2 * 4096 + tid * 16;   // 64B contiguous/lane
      float4_t v0 = *(const float4_t*)(src);
      float4_t v1 = *(const float4_t*)(src + 4);
      float4_t v2 = *(const float4_t*)(src + 8);
      float4_t v3 = *(const float4_t*)(src + 12);
#pragma unroll
      for (int j = 0; j < 4; ++j) {
#pragma unroll
        for (int l = 0; l < 4; ++l) {
          acc[j][l]      += gv[j] * v0[l];
          acc[j][4 + l]  += gv[j] * v1[l];
          acc[j][8 + l]  += gv[j] * v2[l];
          acc[j][12 + l] += gv[j] * v3[l];
        }
      }
    }

    int b23 = tid >> 2;
    int a23base = (tid & 3) * 16;
#pragma unroll
    for (int j = 0; j < 4; ++j) {
      short8_t o0, o1;
#pragma unroll
      for (int i = 0; i < 8; ++i) {
        o0[i] = (short)f2bf(acc[j][i]);
        o1[i] = (short)f2bf(acc[j][8 + i]);
      }
      size_t base = (size_t)((g * 4 + j) * 64 + b23) * GK + a01 * 64 + a23base;
      *(short8_t*)(Mt + base) = o0;
      *(short8_t*)(Mt + base + 8) = o1;
    }
  } else {
    int i = ((bid - 1024) * 256 + tid) * 8;
    float4_t a = *(const float4_t*)(x + i);
    float4_t b = *(const float4_t*)(x + i + 4);
    short8_t o;
    o[0] = (short)f2bf(a[0]); o[1] = (short)f2bf(a[1]);
    o[2] = (short)f2bf(a[2]); o[3] = (short)f2bf(a[3]);
    o[4] = (short)f2bf(b[0]); o[5] = (short)f2bf(b[1]);
    o[6] = (short)f2bf(b[2]); o[7] = (short)f2bf(b[3]);
    *(short8_t*)(xb + i) = o;
  }
}

// ---------------------------------------------------------------------------
// Kernel 3: C = relu(A @ Bt^T + bias). A:[M][K] bf16, Bt:[N][K] bf16.
//
// 256x256 tile, BK=64, 8 waves (2M x 4N), 512 threads, 128 KiB LDS
// (buf0 = even K-tiles, buf1 = odd). Read-ahead pipeline, 4 phases/tile:
//   q0: RD quad1 -> alt frags | stage A0(t+1)->other | MFMA quad0 | bar
//   q1: RD quad2 | stage A1(t+1)->other, B0(t+2)->cur | MFMA quad1 | bar
//   q2: RD quad3 | stage B1(t+2)->cur | MFMA quad2 | vmcnt(4) | bar
//   q3: RD B(t+1) all + quad0(t+1) from other | MFMA quad3 | bar
// Hazard proofs:
//   - region free-for-stage: a quad's ds_reads complete before that wave's
//     consuming MFMA (compiler lgkm wait); all waves' by the post-MFMA
//     barrier. B[cur] last consumed at q0 -> stage from q1. A[cur] last
//     consumed at q3 -> A(t+2) staged at (t+1)q0/q1 (into what is then the
//     other buffer). A(t+1)->other at q0: other's A last read (t-1)q2,
//     consumed (t-1)q3, free ✓.
//   - landing: vmcnt(4) at q2-end: outstanding <=12 = [A0,A1(t+1), B0,B1(t+2)]
//     + <=4 carried [B(t+1)]; first 8 = B(t+1)+A(t+1), exactly what q3's
//     read-ahead touches. Tail (t+2>=NT): vmcnt(0).
// One barrier per phase; sched_barrier(0) after each pins stage/read motion
// across sync points. setprio(1) around MFMA clusters (T5).
// LDS rotation swizzle (R5, 0 conflicts) unchanged. XCD swizzle unchanged.
// ---------------------------------------------------------------------------
__global__ __launch_bounds__(512, 2) void gemm_bias_relu(
    const unsigned short* __restrict__ A, const unsigned short* __restrict__ Bt,
    const float* __restrict__ bias, float* __restrict__ C) {
  extern __shared__ __align__(16) unsigned short lds[];

  const int tid = threadIdx.x;
  const int bswz = blockIdx.x;
  const int xcd = bswz & 7, li = bswz >> 3;
  const int row0 = ((xcd >> 1) * 4 + (li >> 3)) * 256;
  const int col0 = ((xcd & 1) * 8 + (li & 7)) * 256;
  const int wave = tid >> 6, lane = tid & 63;
  const int wm = wave >> 2, wn = wave & 3;
  const int half = lane >> 4, mrow = lane & 15;

  // Staging invariants: chunk c = q*512+tid; r=c>>3, p=c&7, h=(p-r)&7.
  const int r0 = tid >> 3, p0 = tid & 7, h0 = (p0 - r0) & 7;
  const unsigned short* Abase = A + (size_t)(row0 + r0) * GK + h0 * 8;
  const unsigned short* Bbase = Bt + (size_t)(col0 + r0) * GK + h0 * 8;
  const int dA = r0 * 64 + p0 * 8;   // shorts; wave-linear: = tid*16 bytes
  const int dB = dA + 16384;

#define GLD(SRC, DST)                                                  \
  __builtin_amdgcn_global_load_lds(                                    \
      (const __attribute__((address_space(1))) void*)(SRC),            \
      (__attribute__((address_space(3))) void*)(lds + (DST)), 16, 0, 0)
#define STAGE_A(G, KT, BUF)                                            \
  do {                                                                 \
    const unsigned short* s_ = Abase + (size_t)(G) * 128 * GK + (KT) * 64; \
    GLD(s_, (BUF) * 32768 + (G) * 8192 + dA);                          \
    GLD(s_ + (size_t)64 * GK, (BUF) * 32768 + (G) * 8192 + dA + 4096); \
  } while (0)
#define STAGE_B(G, KT, BUF)                                            \
  do {                                                                 \
    const unsigned short* s_ = Bbase + (size_t)(G) * 128 * GK + (KT) * 64; \
    GLD(s_, (BUF) * 32768 + (G) * 8192 + dB);                          \
    GLD(s_ + (size_t)64 * GK, (BUF) * 32768 + (G) * 8192 + dB + 4096); \
  } while (0)

  // Fragment read offsets (shorts). r%8 is m-invariant -> single base,
  // ks=1 flips rotation bit2 -> ^32 shorts; frag m adds m*1024.
  const int arow = wm * 128 + mrow;
  const int aoff0 = arow * 64 + ((half + arow) & 7) * 8;
  const int aoff1 = aoff0 ^ 32;
  const int brow = wn * 64 + mrow;
  const int boff0 = 16384 + brow * 64 + ((half + brow) & 7) * 8;
  const int boff1 = boff0 ^ 32;

  // Read quad Q of buffer BUF into DST[4]: DST[ii*2+ks].
#define RD_A(DST, BUF, Q)                                                   \
  do {                                                                      \
    _Pragma("unroll")                                                       \
    for (int ii = 0; ii < 2; ++ii) {                                        \
      DST[ii * 2 + 0] =                                                     \
          *(const short8_t*)&lds[(BUF)*32768 + aoff0 + (2*(Q)+ii) * 1024];  \
      DST[ii * 2 + 1] =                                                     \
          *(const short8_t*)&lds[(BUF)*32768 + aoff1 + (2*(Q)+ii) * 1024];  \
    }                                                                       \
  } while (0)
#define RD_B(DST, BUF)                                                      \
  do {                                                                      \
    _Pragma("unroll")                                                       \
    for (int n = 0; n < 4; ++n) {                                           \
      DST[n * 2 + 0] =                                                      \
          *(const short8_t*)&lds[(BUF)*32768 + boff0 + n * 1024];           \
      DST[n * 2 + 1] =                                                      \
          *(const short8_t*)&lds[(BUF)*32768 + boff1 + n * 1024];           \
    }                                                                       \
  } while (0)
#define MFMA_Q(Q, AF, BV)                                                   \
  do {                                                                      \
    __builtin_amdgcn_s_setprio(1);                                          \
    _Pragma("unroll")                                                       \
    for (int ks = 0; ks < 2; ++ks)                                          \
      _Pragma("unroll")                                                     \
      for (int ii = 0; ii < 2; ++ii)                                        \
        _Pragma("unroll")                                                   \
        for (int n = 0; n < 4; ++n)                                         \
          acc[2*(Q)+ii][n] = __builtin_amdgcn_mfma_f32_16x16x32_bf16(       \
              AF[ii * 2 + ks], BV[n * 2 + ks], acc[2*(Q)+ii][n], 0, 0, 0);  \
    __builtin_amdgcn_s_setprio(0);                                          \
  } while (0)
#define BAR()                                                               \
  do {                                                                      \
    __builtin_amdgcn_s_barrier();                                           \
    __builtin_amdgcn_sched_barrier(0);                                      \
  } while (0)

  float4_t acc[8][4];
#pragma unroll
  for (int i = 0; i < 8; ++i)
#pragma unroll
    for (int n = 0; n < 4; ++n) acc[i][n] = (float4_t){0.f, 0.f, 0.f, 0.f};

  short8_t b0v[8], b1v[8], afE[4], afO[4];

  // Prologue: tile0 -> buf0 (8 loads), B(1) -> buf1 (4 loads).
  // vmcnt(4): tile0 landed, B(1) outstanding. Then read-ahead tile0 quad0.
  STAGE_A(0, 0, 0); STAGE_A(1, 0, 0); STAGE_B(0, 0, 0); STAGE_B(1, 0, 0);
  STAGE_B(0, 1, 1); STAGE_B(1, 1, 1);
  asm volatile("s_waitcnt vmcnt(4)" ::: "memory");
  BAR();
  RD_B(b0v, 0);
  RD_A(afE, 0, 0);

  for (int kt = 0; kt < NT; kt += 2) {
    // ================= tile kt (buf0) =================
    // q0
    RD_A(afO, 0, 1);
    STAGE_A(0, kt + 1, 1);
    MFMA_Q(0, afE, b0v);
    BAR();
    // q1
    RD_A(afE, 0, 2);
    STAGE_A(1, kt + 1, 1);
    if (kt + 2 < NT) STAGE_B(0, kt + 2, 0);
    MFMA_Q(1, afO, b0v);
    BAR();
    // q2
    RD_A(afO, 0, 3);
    if (kt + 2 < NT) STAGE_B(1, kt + 2, 0);
    MFMA_Q(2, afE, b0v);
    if (kt + 2 < NT)
      asm volatile("s_waitcnt vmcnt(4)" ::: "memory");
    else
      asm volatile("s_waitcnt vmcnt(0)" ::: "memory");
    BAR();
    // q3: read-ahead tile kt+1 (buf1)
    RD_B(b1v, 1);
    RD_A(afE, 1, 0);
    MFMA_Q(3, afO, b0v);
    BAR();

    // ================= tile kt+1 (buf1) =================
    // q0
    RD_A(afO, 1, 1);
    if (kt + 2 < NT) STAGE_A(0, kt + 2, 0);
    MFMA_Q(0, afE, b1v);
    BAR();
    // q1
    RD_A(afE, 1, 2);
    if (kt + 2 < NT) STAGE_A(1, kt + 2, 0);
    if (kt + 3 < NT) STAGE_B(0, kt + 3, 1);
    MFMA_Q(1, afO, b1v);
    BAR();
    // q2
    RD_A(afO, 1, 3);
    if (kt + 3 < NT) STAGE_B(1, kt + 3, 1);
    MFMA_Q(2, afE, b1v);
    if (kt + 3 < NT)
      asm volatile("s_waitcnt vmcnt(4)" ::: "memory");
    else
      asm volatile("s_waitcnt vmcnt(0)" ::: "memory");
    BAR();
    // q3: read-ahead tile kt+2 (buf0)
    if (kt + 2 < NT) { RD_B(b0v, 0); RD_A(afE, 0, 0); }
    MFMA_Q(3, afO, b1v);
    BAR();
  }

#undef BAR
#undef MFMA_Q
#undef RD_B
#undef RD_A
#undef STAGE_B
#undef STAGE_A
#undef GLD

  // Epilogue: C/D layout col=lane&15, row=(lane>>4)*4+reg. Fuse bias+relu.
#pragma unroll
  for (int n = 0; n < 4; ++n) {
    int col = col0 + wn * 64 + n * 16 + mrow;
    float bcol = bias[col];
#pragma unroll
    for (int i = 0; i < 8; ++i) {
#pragma unroll
      for (int r = 0; r < 4; ++r) {
        int row = row0 + wm * 128 + i * 16 + half * 4 + r;
        float v = acc[i][n][r] + bcol;
        C[(size_t)row * GN + col] = v > 0.f ? v : 0.f;
      }
    }
  }
}

// ---------------------------------------------------------------------------
extern "C" void kernel_launch(void* const* d_in, const int* in_sizes, int n_in,
                              void* d_out, int out_size, void* d_ws, size_t ws_size,
                              hipStream_t stream) {
  const float* x  = (const float*)d_in[0];
  const float* c0 = (const float*)d_in[1];
  const float* c1 = (const float*)d_in[2];
  const float* c2 = (const float*)d_in[3];
  const float* c3 = (const float*)d_in[4];
  const float* b  = (const float*)d_in[5];
  float* out = (float*)d_out;

  // Workspace layout: [xb 32MB][Mt 32MB][G01 256KB][G23t 256KB]
  unsigned short* xb = (unsigned short*)d_ws;
  unsigned short* Mt = (unsigned short*)((char*)d_ws + (32u << 20));
  float* G01 = (float*)((char*)d_ws + (64u << 20));
  float* G23t = G01 + 65536;

  static bool lds_configured = false;
  if (!lds_configured) {
    (void)hipFuncSetAttribute((const void*)gemm_bias_relu,
                              hipFuncAttributeMaxDynamicSharedMemorySize,
                              131072);
    lds_configured = true;
  }

  prep_kernel<<<512, 256, 0, stream>>>(c0, c1, c2, c3, G01, G23t);
  mt_convert<<<1024 + (GM * GK) / (256 * 8), 256, 0, stream>>>(
      G01, G23t, Mt, x, xb);
  gemm_bias_relu<<<(GM / 256) * (GN / 256), 512, 131072, stream>>>(
      xb, Mt, b, out);
}